// Round 1
// baseline (133.131 us; speedup 1.0000x reference)
//
#include <hip/hip_runtime.h>

#define DEV __device__ __forceinline__

struct C2 { float r, i; };

// ---------------------------------------------------------------------------
// State layout: one batch element per 16-lane group; lane holds 16 complex
// amps (pr[16], pi[16]). Flat amplitude index i = (sub<<4) | s, sub = lane&15.
// Reference qubit q maps to bit (7-q) of i:
//   q0..q3 -> lane bits 3..0   (cross-lane, shfl_xor masks 8,4,2,1)
//   q4..q7 -> s bits 3..0      (in-lane, masks 8,4,2,1)
// ---------------------------------------------------------------------------

template<int P>
DEV void ry_cross(float* pr, float* pi, float gc, float gs, int lane) {
  const float cb = ((lane >> P) & 1) ? gs : -gs;
  #pragma unroll
  for (int s = 0; s < 16; ++s) {
    float br = __shfl_xor(pr[s], 1 << P);
    float bi = __shfl_xor(pi[s], 1 << P);
    pr[s] = gc * pr[s] + cb * br;
    pi[s] = gc * pi[s] + cb * bi;
  }
}

template<int M>
DEV void ry_in(float* pr, float* pi, float gc, float gs) {
  #pragma unroll
  for (int s = 0; s < 16; ++s) if (!(s & M)) {
    const int s1 = s | M;
    float ar = pr[s], ai = pi[s], br = pr[s1], bi = pi[s1];
    pr[s]  = gc * ar - gs * br;  pi[s]  = gc * ai - gs * bi;
    pr[s1] = gs * ar + gc * br;  pi[s1] = gs * ai + gc * bi;
  }
}

// CX control cross-lane(PC), target cross-lane(PT)
template<int PC, int PT>
DEV void cx_cc(float* pr, float* pi, int lane) {
  const bool h = (lane >> PC) & 1;
  #pragma unroll
  for (int s = 0; s < 16; ++s) {
    float tr = __shfl_xor(pr[s], 1 << PT);
    float ti = __shfl_xor(pi[s], 1 << PT);
    pr[s] = h ? tr : pr[s];
    pi[s] = h ? ti : pi[s];
  }
}

// CX control cross-lane(PC), target in-lane mask MT
template<int PC, int MT>
DEV void cx_ci(float* pr, float* pi, int lane) {
  const bool h = (lane >> PC) & 1;
  #pragma unroll
  for (int s = 0; s < 16; ++s) if (!(s & MT)) {
    const int s1 = s | MT;
    float ar = pr[s], br = pr[s1];
    pr[s] = h ? br : ar;  pr[s1] = h ? ar : br;
    float ai = pi[s], bi = pi[s1];
    pi[s] = h ? bi : ai;  pi[s1] = h ? ai : bi;
  }
}

// CX control in-lane MC, target in-lane MT
template<int MC, int MT>
DEV void cx_ii(float* pr, float* pi) {
  #pragma unroll
  for (int s = 0; s < 16; ++s) if ((s & MC) && !(s & MT)) {
    const int s1 = s | MT;
    float t;
    t = pr[s]; pr[s] = pr[s1]; pr[s1] = t;
    t = pi[s]; pi[s] = pi[s1]; pi[s1] = t;
  }
}

// CX control in-lane MC, target cross-lane(PT)
template<int MC, int PT>
DEV void cx_ic(float* pr, float* pi) {
  #pragma unroll
  for (int s = 0; s < 16; ++s) if (s & MC) {
    pr[s] = __shfl_xor(pr[s], 1 << PT);
    pi[s] = __shfl_xor(pi[s], 1 << PT);
  }
}

// ---- fused 4x4 entangler U4 (stored in LDS, row-major, complex) -----------
// basis m = (b_qc<<1) | b_qt

template<int PC, int PT>  // both qubits cross-lane
DEV void u4_cc(float* pr, float* pi, const float* cw, int lay, int lane) {
  const int bc = (lane >> PC) & 1, bt = (lane >> PT) & 1;
  const int r = (bc << 1) | bt;
  const int base = (lay * 16 + r * 4) * 2;
  const float w0r = cw[base + (r ^ 0) * 2], w0i = cw[base + (r ^ 0) * 2 + 1];
  const float w1r = cw[base + (r ^ 1) * 2], w1i = cw[base + (r ^ 1) * 2 + 1];
  const float w2r = cw[base + (r ^ 2) * 2], w2i = cw[base + (r ^ 2) * 2 + 1];
  const float w3r = cw[base + (r ^ 3) * 2], w3i = cw[base + (r ^ 3) * 2 + 1];
  #pragma unroll
  for (int s = 0; s < 16; ++s) {
    float ar = pr[s], ai = pi[s];
    float tr = __shfl_xor(ar, 1 << PT), ti = __shfl_xor(ai, 1 << PT);
    float cr = __shfl_xor(ar, 1 << PC), ci = __shfl_xor(ai, 1 << PC);
    float ur = __shfl_xor(tr, 1 << PC), ui = __shfl_xor(ti, 1 << PC);
    pr[s] = w0r*ar - w0i*ai + w1r*tr - w1i*ti + w2r*cr - w2i*ci + w3r*ur - w3i*ui;
    pi[s] = w0r*ai + w0i*ar + w1r*ti + w1i*tr + w2r*ci + w2i*cr + w3r*ui + w3i*ur;
  }
}

template<int PC, int MT>  // qc cross-lane, qt in-lane
DEV void u4_ci(float* pr, float* pi, const float* cw, int lay, int lane) {
  const int bc = (lane >> PC) & 1;
  const int r0 = bc << 1, r1 = r0 | 1;
  const int b0 = (lay * 16 + r0 * 4) * 2;
  const int b1 = (lay * 16 + r1 * 4) * 2;
  const float A0r = cw[b0 + (r0 ^ 0) * 2], A0i = cw[b0 + (r0 ^ 0) * 2 + 1];
  const float A1r = cw[b0 + (r0 ^ 1) * 2], A1i = cw[b0 + (r0 ^ 1) * 2 + 1];
  const float A2r = cw[b0 + (r0 ^ 2) * 2], A2i = cw[b0 + (r0 ^ 2) * 2 + 1];
  const float A3r = cw[b0 + (r0 ^ 3) * 2], A3i = cw[b0 + (r0 ^ 3) * 2 + 1];
  const float B0r = cw[b1 + (r1 ^ 0) * 2], B0i = cw[b1 + (r1 ^ 0) * 2 + 1];
  const float B1r = cw[b1 + (r1 ^ 1) * 2], B1i = cw[b1 + (r1 ^ 1) * 2 + 1];
  const float B2r = cw[b1 + (r1 ^ 2) * 2], B2i = cw[b1 + (r1 ^ 2) * 2 + 1];
  const float B3r = cw[b1 + (r1 ^ 3) * 2], B3i = cw[b1 + (r1 ^ 3) * 2 + 1];
  #pragma unroll
  for (int s = 0; s < 16; ++s) if (!(s & MT)) {
    const int s1 = s | MT;
    float ar = pr[s], ai = pi[s], br = pr[s1], bi = pi[s1];
    float xar = __shfl_xor(ar, 1 << PC), xai = __shfl_xor(ai, 1 << PC);
    float xbr = __shfl_xor(br, 1 << PC), xbi = __shfl_xor(bi, 1 << PC);
    pr[s]  = A0r*ar - A0i*ai + A1r*br - A1i*bi + A2r*xar - A2i*xai + A3r*xbr - A3i*xbi;
    pi[s]  = A0r*ai + A0i*ar + A1r*bi + A1i*br + A2r*xai + A2i*xar + A3r*xbi + A3i*xbr;
    pr[s1] = B0r*br - B0i*bi + B1r*ar - B1i*ai + B2r*xbr - B2i*xbi + B3r*xar - B3i*xai;
    pi[s1] = B0r*bi + B0i*br + B1r*ai + B1i*ar + B2r*xbi + B2i*xbr + B3r*xai + B3i*xar;
  }
}

template<int MC, int MT>  // both in-lane
DEV void u4_ii(float* pr, float* pi, const float* cw, int lay) {
  float u[32];
  #pragma unroll
  for (int k = 0; k < 32; ++k) u[k] = cw[lay * 32 + k];
  #pragma unroll
  for (int s = 0; s < 16; ++s) if (!(s & (MC | MT))) {
    const int s0 = s, s1 = s | MT, s2 = s | MC, s3 = s | MC | MT;
    float v0r = pr[s0], v0i = pi[s0], v1r = pr[s1], v1i = pi[s1];
    float v2r = pr[s2], v2i = pi[s2], v3r = pr[s3], v3i = pi[s3];
    float n0r = u[0]*v0r - u[1]*v0i + u[2]*v1r - u[3]*v1i + u[4]*v2r - u[5]*v2i + u[6]*v3r - u[7]*v3i;
    float n0i = u[0]*v0i + u[1]*v0r + u[2]*v1i + u[3]*v1r + u[4]*v2i + u[5]*v2r + u[6]*v3i + u[7]*v3r;
    float n1r = u[8]*v0r - u[9]*v0i + u[10]*v1r - u[11]*v1i + u[12]*v2r - u[13]*v2i + u[14]*v3r - u[15]*v3i;
    float n1i = u[8]*v0i + u[9]*v0r + u[10]*v1i + u[11]*v1r + u[12]*v2i + u[13]*v2r + u[14]*v3i + u[15]*v3r;
    float n2r = u[16]*v0r - u[17]*v0i + u[18]*v1r - u[19]*v1i + u[20]*v2r - u[21]*v2i + u[22]*v3r - u[23]*v3i;
    float n2i = u[16]*v0i + u[17]*v0r + u[18]*v1i + u[19]*v1r + u[20]*v2i + u[21]*v2r + u[22]*v3i + u[23]*v3r;
    float n3r = u[24]*v0r - u[25]*v0i + u[26]*v1r - u[27]*v1i + u[28]*v2r - u[29]*v2i + u[30]*v3r - u[31]*v3i;
    float n3i = u[24]*v0i + u[25]*v0r + u[26]*v1i + u[27]*v1r + u[28]*v2i + u[29]*v2r + u[30]*v3i + u[31]*v3r;
    pr[s0] = n0r; pi[s0] = n0i; pr[s1] = n1r; pi[s1] = n1i;
    pr[s2] = n2r; pi[s2] = n2i; pr[s3] = n3r; pi[s3] = n3i;
  }
}

// ---- U3 single-qubit gates ------------------------------------------------

DEV void u3_make(float t, float p, float l, C2* u) {
  float c = __cosf(0.5f * t), s = __sinf(0.5f * t);
  float cp = __cosf(p), sp = __sinf(p);
  float cl = __cosf(l), sl = __sinf(l);
  float cpl = __cosf(p + l), spl = __sinf(p + l);
  u[0] = C2{c, 0.0f};
  u[1] = C2{-cl * s, -sl * s};
  u[2] = C2{cp * s, sp * s};
  u[3] = C2{cpl * c, spl * c};
}

template<int P>
DEV void u3_cross(float* pr, float* pi, const C2* u, int lane) {
  const bool h = (lane >> P) & 1;
  const float car = h ? u[3].r : u[0].r, cai = h ? u[3].i : u[0].i;
  const float cbr = h ? u[2].r : u[1].r, cbi = h ? u[2].i : u[1].i;
  #pragma unroll
  for (int s = 0; s < 16; ++s) {
    float br = __shfl_xor(pr[s], 1 << P);
    float bi = __shfl_xor(pi[s], 1 << P);
    float ar = pr[s], ai = pi[s];
    pr[s] = car*ar - cai*ai + cbr*br - cbi*bi;
    pi[s] = car*ai + cai*ar + cbr*bi + cbi*br;
  }
}

template<int M>
DEV void u3_in(float* pr, float* pi, const C2* u) {
  #pragma unroll
  for (int s = 0; s < 16; ++s) if (!(s & M)) {
    const int s1 = s | M;
    float ar = pr[s], ai = pi[s], br = pr[s1], bi = pi[s1];
    pr[s]  = u[0].r*ar - u[0].i*ai + u[1].r*br - u[1].i*bi;
    pi[s]  = u[0].r*ai + u[0].i*ar + u[1].r*bi + u[1].i*br;
    pr[s1] = u[2].r*ar - u[2].i*ai + u[3].r*br - u[3].i*bi;
    pi[s1] = u[2].r*ai + u[2].i*ar + u[3].r*bi + u[3].i*br;
  }
}

// ---- CRX: on control=1, new_a = c*a - i*s*b -------------------------------

template<int PC, int PT>
DEV void crx_cc(float* pr, float* pi, float c, float s, int lane) {
  const bool h = (lane >> PC) & 1;
  const float cc = h ? c : 1.0f;
  const float ss = h ? s : 0.0f;
  #pragma unroll
  for (int k = 0; k < 16; ++k) {
    float br = __shfl_xor(pr[k], 1 << PT);
    float bi = __shfl_xor(pi[k], 1 << PT);
    float ar = pr[k], ai = pi[k];
    pr[k] = cc * ar + ss * bi;
    pi[k] = cc * ai - ss * br;
  }
}

template<int PC, int MT>
DEV void crx_ci(float* pr, float* pi, float c, float s, int lane) {
  const bool h = (lane >> PC) & 1;
  const float cc = h ? c : 1.0f;
  const float ss = h ? s : 0.0f;
  #pragma unroll
  for (int k = 0; k < 16; ++k) if (!(k & MT)) {
    const int k1 = k | MT;
    float ar = pr[k], ai = pi[k], br = pr[k1], bi = pi[k1];
    pr[k]  = cc * ar + ss * bi;
    pi[k]  = cc * ai - ss * br;
    pr[k1] = cc * br + ss * ai;
    pi[k1] = cc * bi - ss * ar;
  }
}

template<int MC, int MT>
DEV void crx_ii(float* pr, float* pi, float c, float s) {
  #pragma unroll
  for (int k = 0; k < 16; ++k) if ((k & MC) && !(k & MT)) {
    const int k1 = k | MT;
    float ar = pr[k], ai = pi[k], br = pr[k1], bi = pi[k1];
    pr[k]  = c * ar + s * bi;
    pi[k]  = c * ai - s * br;
    pr[k1] = c * br + s * ai;
    pi[k1] = c * bi - s * ar;
  }
}

// ---- <Z3>, <Z7> -----------------------------------------------------------

DEV void expz37(const float* pr, const float* pi, int lane, float& z3, float& z7) {
  float t3 = 0.0f, t7 = 0.0f;
  #pragma unroll
  for (int s = 0; s < 16; ++s) {
    float p = pr[s] * pr[s] + pi[s] * pi[s];
    t3 += p;
    t7 += (s & 1) ? -p : p;
  }
  t3 = (lane & 1) ? -t3 : t3;   // qubit 3 <-> lane bit 0
  #pragma unroll
  for (int m = 1; m < 16; m <<= 1) {
    t3 += __shfl_xor(t3, m);
    t7 += __shfl_xor(t7, m);
  }
  z3 = t3; z7 = t7;
}

// ---------------------------------------------------------------------------

__global__ __launch_bounds__(256, 2)
void qcnn_kernel(const float* __restrict__ x,
                 const float* __restrict__ rz_p, const float* __restrict__ ry_p,
                 const float* __restrict__ ry2_p, const float* __restrict__ crx_p,
                 const float* __restrict__ u3_p, const float* __restrict__ u3b_p,
                 const float* __restrict__ W1, const float* __restrict__ b1,
                 const float* __restrict__ W2, const float* __restrict__ b2,
                 float* __restrict__ out, int B) {
  __shared__ float cw[64];   // 2 layers x 16 complex entries of fused U4

  const int tid  = threadIdx.x;
  const int lane = tid & 63;
  const int wave = tid >> 6;
  const int grp  = lane >> 4;
  const int sub  = lane & 15;
  const int elem = blockIdx.x * 16 + wave * 4 + grp;
  const int elemc = elem < B ? elem : (B - 1);

  // ---- fused U4 chain: lanes 0..31, one complex entry per lane; every wave
  // computes identical values, duplicate LDS writes are benign ----
  if (lane < 32) {
    const int lay = lane >> 4, e = lane & 15, i4 = e >> 2, j4 = e & 3;
    const int base = lane & 48;
    const float c45 = 0.70710678118654752f;
    float rz = rz_p[lay], ry = ry_p[lay], ry2 = ry2_p[lay];
    // G1 = I (x) RZ(-pi/2): diag, bt=0 -> e^{+i pi/4}
    float mr = (i4 == j4) ? c45 : 0.0f;
    float mi = (i4 == j4) ? ((i4 & 1) ? -c45 : c45) : 0.0f;
    // G2 = CX(ctrl qt, tgt qc): rows 1<->3
    { int t = (i4 & 1) ? (i4 ^ 2) : i4; int src = base | (t << 2) | j4;
      mr = __shfl(mr, src); mi = __shfl(mi, src); }
    // G3 = RZ(rz) (x) I
    { float cz = __cosf(0.5f * rz), sz = __sinf(0.5f * rz);
      float di = (i4 & 2) ? sz : -sz;
      float nr = cz * mr - di * mi, ni = cz * mi + di * mr; mr = nr; mi = ni; }
    // G4 = I (x) RY(ry)
    { float cy = __cosf(0.5f * ry), sy = __sinf(0.5f * ry);
      int src = base | ((i4 ^ 1) << 2) | j4;
      float orr = __shfl(mr, src), oii = __shfl(mi, src);
      float sg = (i4 & 1) ? sy : -sy;
      mr = cy * mr + sg * orr; mi = cy * mi + sg * oii; }
    // G5 = CX(ctrl qc, tgt qt): rows 2<->3
    { int t = (i4 & 2) ? (i4 ^ 1) : i4; int src = base | (t << 2) | j4;
      mr = __shfl(mr, src); mi = __shfl(mi, src); }
    // G6 = I (x) RY(ry2)
    { float cy = __cosf(0.5f * ry2), sy = __sinf(0.5f * ry2);
      int src = base | ((i4 ^ 1) << 2) | j4;
      float orr = __shfl(mr, src), oii = __shfl(mi, src);
      float sg = (i4 & 1) ? sy : -sy;
      mr = cy * mr + sg * orr; mi = cy * mi + sg * oii; }
    // G7 = G2
    { int t = (i4 & 1) ? (i4 ^ 2) : i4; int src = base | (t << 2) | j4;
      mr = __shfl(mr, src); mi = __shfl(mi, src); }
    // G8 = RZ(pi/2) (x) I
    { float di = (i4 & 2) ? c45 : -c45;
      float nr = c45 * mr - di * mi, ni = c45 * mi + di * mr; mr = nr; mi = ni; }
    cw[(lay * 16 + e) * 2]     = mr;
    cw[(lay * 16 + e) * 2 + 1] = mi;
  }

  // ---- encoding angles: lane sub holds angles 2*sub, 2*sub+1 of its element
  float2 aa = ((const float2*)x)[(size_t)elemc * 16 + sub];
  float ch0 = __cosf(0.5f * aa.x), sh0 = __sinf(0.5f * aa.x);
  float ch1 = __cosf(0.5f * aa.y), sh1 = __sinf(0.5f * aa.y);

  // ---- |0...0> ----
  float pr[16], pi[16];
  #pragma unroll
  for (int s = 0; s < 16; ++s) { pr[s] = 0.0f; pi[s] = 0.0f; }
  pr[0] = (sub == 0) ? 1.0f : 0.0f;

  // ---- encode: 4 cycles of RY(x) on q0..q7 + CNOT ring ----
  #pragma unroll 1
  for (int c = 0; c < 4; ++c) {
    const int sb = lane & 48;
    float gc, gs;
    // q0: k=8c   -> holder sub=4c+0, comp 0
    gc = __shfl(ch0, sb | (c * 4 + 0)); gs = __shfl(sh0, sb | (c * 4 + 0));
    ry_cross<3>(pr, pi, gc, gs, lane);
    // q1
    gc = __shfl(ch1, sb | (c * 4 + 0)); gs = __shfl(sh1, sb | (c * 4 + 0));
    ry_cross<2>(pr, pi, gc, gs, lane);
    // q2
    gc = __shfl(ch0, sb | (c * 4 + 1)); gs = __shfl(sh0, sb | (c * 4 + 1));
    ry_cross<1>(pr, pi, gc, gs, lane);
    // q3
    gc = __shfl(ch1, sb | (c * 4 + 1)); gs = __shfl(sh1, sb | (c * 4 + 1));
    ry_cross<0>(pr, pi, gc, gs, lane);
    // q4
    gc = __shfl(ch0, sb | (c * 4 + 2)); gs = __shfl(sh0, sb | (c * 4 + 2));
    ry_in<8>(pr, pi, gc, gs);
    // q5
    gc = __shfl(ch1, sb | (c * 4 + 2)); gs = __shfl(sh1, sb | (c * 4 + 2));
    ry_in<4>(pr, pi, gc, gs);
    // q6
    gc = __shfl(ch0, sb | (c * 4 + 3)); gs = __shfl(sh0, sb | (c * 4 + 3));
    ry_in<2>(pr, pi, gc, gs);
    // q7
    gc = __shfl(ch1, sb | (c * 4 + 3)); gs = __shfl(sh1, sb | (c * 4 + 3));
    ry_in<1>(pr, pi, gc, gs);
    // CNOT ring (q, q+1 mod 8), q = 0..7
    cx_cc<3, 2>(pr, pi, lane);   // (0,1)
    cx_cc<2, 1>(pr, pi, lane);   // (1,2)
    cx_cc<1, 0>(pr, pi, lane);   // (2,3)
    cx_ci<0, 8>(pr, pi, lane);   // (3,4)
    cx_ii<8, 4>(pr, pi);         // (4,5)
    cx_ii<4, 2>(pr, pi);         // (5,6)
    cx_ii<2, 1>(pr, pi);         // (6,7)
    cx_ic<1, 3>(pr, pi);         // (7,0)
  }

  // ---- psi1 = copy of encoded state ----
  float qr[16], qi[16];
  #pragma unroll
  for (int s = 0; s < 16; ++s) { qr[s] = pr[s]; qi[s] = pi[s]; }

  __syncthreads();  // cw (fused U4) ready

  // ---- psi0 layer 0 (aq = 0..7): pairs p0:(0,1)(2,3)(4,5)(6,7) p1:(1,2)(3,4)(5,6)
  u4_cc<3, 2>(pr, pi, cw, 0, lane);
  u4_cc<1, 0>(pr, pi, cw, 0, lane);
  u4_ii<8, 4>(pr, pi, cw, 0);
  u4_ii<2, 1>(pr, pi, cw, 0);
  u4_cc<2, 1>(pr, pi, cw, 0, lane);
  u4_ci<0, 8>(pr, pi, cw, 0, lane);
  u4_ii<4, 2>(pr, pi, cw, 0);
  {
    C2 u[4]; u3_make(u3_p[0], u3_p[1], u3_p[2], u);
    u3_cross<2>(pr, pi, u, lane);  // q1
    u3_cross<0>(pr, pi, u, lane);  // q3
    u3_in<4>(pr, pi, u);           // q5
    u3_in<1>(pr, pi, u);           // q7
  }
  // ---- psi0 layer 1 (aq = 1,3,5,7): pairs (1,3)(5,7)(3,5)
  u4_cc<2, 0>(pr, pi, cw, 1, lane);
  u4_ii<4, 1>(pr, pi, cw, 1);
  u4_ci<0, 4>(pr, pi, cw, 1, lane);
  {
    C2 u[4]; u3_make(u3_p[3], u3_p[4], u3_p[5], u);
    u3_cross<0>(pr, pi, u, lane);  // q3
    u3_in<1>(pr, pi, u);           // q7
  }

  // ---- psi1 layer 0: CRX ladder + U3b
  {
    float t = crx_p[0];
    float cc = __cosf(0.5f * t), ss = __sinf(0.5f * t);
    crx_cc<3, 2>(qr, qi, cc, ss, lane);
    crx_cc<1, 0>(qr, qi, cc, ss, lane);
    crx_ii<8, 4>(qr, qi, cc, ss);
    crx_ii<2, 1>(qr, qi, cc, ss);
    crx_cc<2, 1>(qr, qi, cc, ss, lane);
    crx_ci<0, 8>(qr, qi, cc, ss, lane);
    crx_ii<4, 2>(qr, qi, cc, ss);
  }
  {
    C2 u[4]; u3_make(u3b_p[0], u3b_p[1], u3b_p[2], u);
    u3_cross<2>(qr, qi, u, lane);
    u3_cross<0>(qr, qi, u, lane);
    u3_in<4>(qr, qi, u);
    u3_in<1>(qr, qi, u);
  }
  // ---- psi1 layer 1
  {
    float t = crx_p[1];
    float cc = __cosf(0.5f * t), ss = __sinf(0.5f * t);
    crx_cc<2, 0>(qr, qi, cc, ss, lane);
    crx_ii<4, 1>(qr, qi, cc, ss);
    crx_ci<0, 4>(qr, qi, cc, ss, lane);
  }
  {
    C2 u[4]; u3_make(u3b_p[3], u3b_p[4], u3b_p[5], u);
    u3_cross<0>(qr, qi, u, lane);
    u3_in<1>(qr, qi, u);
  }

  // ---- features: [z3(psi0), z7(psi0), z3(psi1), z7(psi1)] ----
  float f0, f1, f2, f3;
  expz37(pr, pi, lane, f0, f1);
  expz37(qr, qi, lane, f2, f3);

  // ---- MLP: lane j (=sub, j<15) computes hidden unit j ----
  const int j = (sub < 15) ? sub : 0;
  float acc = W1[j * 4 + 0] * f0 + W1[j * 4 + 1] * f1 +
              W1[j * 4 + 2] * f2 + W1[j * 4 + 3] * f3 + b1[j];
  float e2 = __expf(2.0f * acc);
  float th = (e2 - 1.0f) / (e2 + 1.0f);
  float part = (sub < 15) ? th * W2[j] : 0.0f;
  #pragma unroll
  for (int m = 1; m < 16; m <<= 1) part += __shfl_xor(part, m);

  if (sub == 0 && elem < B) {
    float z = part + b2[0];
    out[elem] = 1.0f / (1.0f + __expf(-z));
  }
}

extern "C" void kernel_launch(void* const* d_in, const int* in_sizes, int n_in,
                              void* d_out, int out_size, void* d_ws, size_t ws_size,
                              hipStream_t stream) {
  (void)n_in; (void)out_size; (void)d_ws; (void)ws_size;
  const float* x     = (const float*)d_in[0];
  const float* rz_p  = (const float*)d_in[1];
  const float* ry_p  = (const float*)d_in[2];
  const float* ry2_p = (const float*)d_in[3];
  const float* crx_p = (const float*)d_in[4];
  const float* u3_p  = (const float*)d_in[5];
  const float* u3b_p = (const float*)d_in[6];
  const float* W1    = (const float*)d_in[7];
  const float* b1    = (const float*)d_in[8];
  const float* W2    = (const float*)d_in[9];
  const float* b2    = (const float*)d_in[10];
  float* out = (float*)d_out;

  const int B = in_sizes[0] / 32;          // 8192
  const int blocks = (B + 15) / 16;        // 16 elements per 256-thread block
  qcnn_kernel<<<dim3(blocks), dim3(256), 0, stream>>>(
      x, rz_p, ry_p, ry2_p, crx_p, u3_p, u3b_p, W1, b1, W2, b2, out, B);
}